// Round 5
// baseline (170.159 us; speedup 1.0000x reference)
//
#include <hip/hip_runtime.h>
#include <hip/hip_cooperative_groups.h>

#define DEG 16
#define APB 64          // atoms per block
#define TPB 256
#define EPS_F 1e-12f

// Single cooperative kernel: edge build + pair energies + block partials +
// grid-wide sync + final reduction. 4 edges per thread.
__global__ __launch_bounds__(TPB) void ManyBodyPotential_85143431675992_kernel(
    const float* __restrict__ pos,      // (n_atoms, 3)
    const int*   __restrict__ target,   // (n_atoms*DEG,) = edge_index[1]
    const int*   __restrict__ elem,     // (n_atoms,)
    const int*   __restrict__ plt,      // (3,3) row-major, symmetric
    const float* __restrict__ k_angle,  // (6,)
    const float* __restrict__ cos0,     // (6,)
    float*       __restrict__ partials, // (gridDim.x,)
    float*       __restrict__ out,
    int n_atoms, int n_blocks)
{
    __shared__ float  ka_tab[9];
    __shared__ float  c0_tab[9];
    __shared__ float4 s4[APB][DEG + 1];   // unit vec + elem-as-float, +1 row pad
    __shared__ float  wsum[4];

    const int t = threadIdx.x;
    if (t < 9) {
        const int p = plt[t];
        ka_tab[t] = k_angle[p];
        c0_tab[t] = cos0[p];
    }

    const int a    = t >> 2;              // local atom 0..63
    const int q    = t & 3;               // quarter: slots 4q..4q+3
    const int atom = blockIdx.x * APB + a;
    const bool active = (atom < n_atoms);

    float ux[4], uy[4], uz[4];
    int   ej[4] = {0, 0, 0, 0};
    if (active) {
        const float pix = pos[atom * 3 + 0];
        const float piy = pos[atom * 3 + 1];
        const float piz = pos[atom * 3 + 2];
        const int4 tj4 = *(const int4*)(target + atom * DEG + q * 4); // 16B aligned
        const int tj[4] = { tj4.x, tj4.y, tj4.z, tj4.w };
        #pragma unroll
        for (int e = 0; e < 4; ++e) {
            const int   n  = tj[e];
            const float dx = pos[n * 3 + 0] - pix;
            const float dy = pos[n * 3 + 1] - piy;
            const float dz = pos[n * 3 + 2] - piz;
            const float r2 = dx * dx + dy * dy + dz * dz;
            // r2==0 (self-edge): reference yields cos=0 for pairs on this
            // edge; a zero unit vector reproduces that exactly.
            const float ri = (r2 > 0.f) ? rsqrtf(r2) : 0.f;
            ux[e] = dx * ri; uy[e] = dy * ri; uz[e] = dz * ri;
            ej[e] = elem[n];
            s4[a][q * 4 + e] = make_float4(ux[e], uy[e], uz[e], (float)ej[e]);
        }
    }
    __syncthreads();

    float acc = 0.0f;
    if (active) {
        // Symmetry: e(j,k)==e(k,j). Circular offsets d=1..7 hit each
        // unordered pair once (weight 2); d=8 pairs are hit twice (weight 1).
        float acc2 = 0.0f, acc8 = 0.0f;
        #pragma unroll
        for (int e = 0; e < 4; ++e) {
            const int   j   = q * 4 + e;
            const int   r   = ej[e] * 3;
            const float ka0 = ka_tab[r + 0], ka1 = ka_tab[r + 1], ka2 = ka_tab[r + 2];
            const float c00 = c0_tab[r + 0], c01 = c0_tab[r + 1], c02 = c0_tab[r + 2];
            #pragma unroll
            for (int d = 1; d <= 8; ++d) {
                const float4 o  = s4[a][(j + d) & 15];
                const float  ka = (o.w == 1.0f) ? ka1 : ((o.w == 2.0f) ? ka2 : ka0);
                const float  c0 = (o.w == 1.0f) ? c01 : ((o.w == 2.0f) ? c02 : c00);
                const float  ct = ux[e] * o.x + uy[e] * o.y + uz[e] * o.z;
                const float  dd = ct - c0;
                const float  en = ka * dd * dd;
                if (d < 8) acc2 += en; else acc8 += en;
            }
        }
        acc = 2.0f * acc2 + acc8;
    }

    #pragma unroll
    for (int off = 32; off > 0; off >>= 1)
        acc += __shfl_down(acc, off, 64);
    if ((t & 63) == 0) wsum[t >> 6] = acc;
    __syncthreads();
    if (t == 0)
        partials[blockIdx.x] = wsum[0] + wsum[1] + wsum[2] + wsum[3];

    cooperative_groups::this_grid().sync();

    if (blockIdx.x == 0) {
        float s = 0.0f;
        for (int i = t; i < n_blocks; i += TPB) s += partials[i];
        #pragma unroll
        for (int off = 32; off > 0; off >>= 1)
            s += __shfl_down(s, off, 64);
        __syncthreads();                      // wsum reuse
        if ((t & 63) == 0) wsum[t >> 6] = s;
        __syncthreads();
        if (t == 0) out[0] = wsum[0] + wsum[1] + wsum[2] + wsum[3];
    }
}

// ---------------- Fallback path (coop launch or ws unavailable) -------------
__global__ void mbp_zero_kernel(float* out) {
    if (threadIdx.x == 0) out[0] = 0.0f;
}

__global__ __launch_bounds__(256) void mbp_fallback_kernel(
    const float* __restrict__ pos, const int* __restrict__ target,
    const int* __restrict__ elem, const int* __restrict__ plt,
    const float* __restrict__ k_angle, const float* __restrict__ cos0,
    float* __restrict__ out, int n_atoms)
{
    __shared__ float  ka_tab[9];
    __shared__ float  c0_tab[9];
    __shared__ float4 s4[16][DEG + 1];
    __shared__ float  wsum[4];
    const int t = threadIdx.x;
    if (t < 9) { const int p = plt[t]; ka_tab[t] = k_angle[p]; c0_tab[t] = cos0[p]; }
    const int a = t >> 4, j = t & 15;
    const int atom = blockIdx.x * 16 + a;
    const bool active = (atom < n_atoms);
    float ux = 0.f, uy = 0.f, uz = 0.f; int ej = 0;
    if (active) {
        const float pix = pos[atom * 3], piy = pos[atom * 3 + 1], piz = pos[atom * 3 + 2];
        const int tj = target[atom * DEG + j];
        const float dx = pos[tj * 3] - pix, dy = pos[tj * 3 + 1] - piy, dz = pos[tj * 3 + 2] - piz;
        const float r2 = dx * dx + dy * dy + dz * dz;
        const float ri = (r2 > 0.f) ? rsqrtf(r2) : 0.f;
        ux = dx * ri; uy = dy * ri; uz = dz * ri;
        ej = elem[tj];
        s4[a][j] = make_float4(ux, uy, uz, (float)ej);
    }
    __syncthreads();
    float acc = 0.0f;
    if (active) {
        const int r = ej * 3;
        const float ka0 = ka_tab[r], ka1 = ka_tab[r + 1], ka2 = ka_tab[r + 2];
        const float c00 = c0_tab[r], c01 = c0_tab[r + 1], c02 = c0_tab[r + 2];
        float acc2 = 0.f, acc8 = 0.f;
        #pragma unroll
        for (int d = 1; d <= 8; ++d) {
            const int k = (j + d) & 15;
            const float4 o = s4[a][k];
            const float ka = (o.w == 1.0f) ? ka1 : ((o.w == 2.0f) ? ka2 : ka0);
            const float c0 = (o.w == 1.0f) ? c01 : ((o.w == 2.0f) ? c02 : c00);
            const float ct = ux * o.x + uy * o.y + uz * o.z;
            const float dd = ct - c0;
            const float en = ka * dd * dd;
            if (d < 8) acc2 += en; else acc8 = en;
        }
        acc = 2.0f * acc2 + acc8;
    }
    #pragma unroll
    for (int off = 32; off > 0; off >>= 1) acc += __shfl_down(acc, off, 64);
    if ((t & 63) == 0) wsum[t >> 6] = acc;
    __syncthreads();
    if (t == 0) atomicAdd(out, wsum[0] + wsum[1] + wsum[2] + wsum[3]);
}

extern "C" void kernel_launch(void* const* d_in, const int* in_sizes, int n_in,
                              void* d_out, int out_size, void* d_ws, size_t ws_size,
                              hipStream_t stream) {
    const float* pos     = (const float*)d_in[0];
    const int*   edge    = (const int*)d_in[1];   // (2, n_edges) flat
    const int*   elem    = (const int*)d_in[2];
    const int*   plt     = (const int*)d_in[3];
    const float* k_angle = (const float*)d_in[4];
    const float* cos0    = (const float*)d_in[5];
    float*       out     = (float*)d_out;

    const int n_atoms = in_sizes[0] / 3;
    const int n_edges = in_sizes[1] / 2;
    const int* target = edge + n_edges;           // edge_index[1]

    const int n_blocks = (n_atoms + APB - 1) / APB;            // 782
    const bool ws_ok = (d_ws != nullptr) &&
                       (ws_size >= (size_t)n_blocks * sizeof(float));

    hipError_t err = hipErrorUnknown;
    if (ws_ok) {
        float* partials = (float*)d_ws;
        void* args[] = {
            (void*)&pos, (void*)&target, (void*)&elem, (void*)&plt,
            (void*)&k_angle, (void*)&cos0, (void*)&partials, (void*)&out,
            (void*)&n_atoms, (void*)&n_blocks
        };
        err = hipLaunchCooperativeKernel(
            (const void*)ManyBodyPotential_85143431675992_kernel,
            dim3(n_blocks), dim3(TPB), args, 0, stream);
    }

    if (err != hipSuccess) {
        // Fallback: classic 2-dispatch path with per-block atomics.
        const int fb_blocks = (n_atoms + 15) / 16;
        mbp_zero_kernel<<<1, 64, 0, stream>>>(out);
        mbp_fallback_kernel<<<fb_blocks, 256, 0, stream>>>(
            pos, target, elem, plt, k_angle, cos0, out, n_atoms);
    }
}

// Round 6
// 81.429 us; speedup vs baseline: 2.0897x; 2.0897x over previous
//
#include <hip/hip_runtime.h>

#define DEG 16
#define APB 16      // atoms per 256-thread block (16 lanes per atom = 1 DPP row)
#define TPB 256

// Rotate within each 16-lane DPP row by D. Direction (ror vs rol) is
// irrelevant for correctness: pair set {j, (j+d)&15} == {j, (j-d)&15}.
template<int D>
__device__ __forceinline__ float dpp_ror(float x) {
    const int r = __builtin_amdgcn_update_dpp(
        0, __float_as_int(x), 0x120 | D, 0xF, 0xF, true);
    return __int_as_float(r);
}

__device__ __forceinline__ float sel3(float ew, float a, float b, float c) {
    return (ew == 1.0f) ? b : ((ew == 2.0f) ? c : a);
}

__global__ __launch_bounds__(TPB) void ManyBodyPotential_85143431675992_kernel(
    const float* __restrict__ pos,      // (n_atoms, 3)
    const int*   __restrict__ target,   // (n_atoms*DEG,) = edge_index[1]
    const int*   __restrict__ elem,     // (n_atoms,)
    const int*   __restrict__ plt,      // (3,3) row-major, symmetric
    const float* __restrict__ k_angle,  // (6,)
    const float* __restrict__ cos0,     // (6,)
    float*       __restrict__ partials, // (gridDim.x,)
    int n_atoms)
{
    __shared__ float wsum[4];

    const int t = threadIdx.x;
    const int a = t >> 4;                 // local atom 0..15 (one DPP row each)
    const int j = t & 15;                 // neighbor slot
    int atom = blockIdx.x * APB + a;
    const bool active = (atom < n_atoms);
    if (!active) atom = n_atoms - 1;      // clamp: keep all 64 lanes executing

    // Uniform folded coefficient tables -> scalar loads + registers (no LDS,
    // no barrier). kf[i]/cf[i] are wave-uniform; constant-indexed -> regs.
    float kf[9], cf[9];
    #pragma unroll
    for (int i = 0; i < 9; ++i) {
        const int p = plt[i];
        kf[i] = k_angle[p];
        cf[i] = cos0[p];
    }

    // Build this thread's edge.
    const float pix = pos[atom * 3 + 0];
    const float piy = pos[atom * 3 + 1];
    const float piz = pos[atom * 3 + 2];
    const int   tj  = target[atom * DEG + j];   // coalesced
    const float dx  = pos[tj * 3 + 0] - pix;
    const float dy  = pos[tj * 3 + 1] - piy;
    const float dz  = pos[tj * 3 + 2] - piz;
    const float r2  = dx * dx + dy * dy + dz * dz;
    // r2==0 (self-edge): reference gives cos=0 for pairs on this edge; a zero
    // unit vector reproduces that exactly.
    const float ri  = (r2 > 0.f) ? rsqrtf(r2) : 0.f;
    const float ux  = dx * ri, uy = dy * ri, uz = dz * ri;
    const int   ej  = elem[tj];
    const float ejf = (float)ej;

    // Select this thread's (ej, *) coefficient row.
    const float ka0 = sel3(ejf, kf[0], kf[3], kf[6]);
    const float ka1 = sel3(ejf, kf[1], kf[4], kf[7]);
    const float ka2 = sel3(ejf, kf[2], kf[5], kf[8]);
    const float c00 = sel3(ejf, cf[0], cf[3], cf[6]);
    const float c01 = sel3(ejf, cf[1], cf[4], cf[7]);
    const float c02 = sel3(ejf, cf[2], cf[5], cf[8]);

    // Pair loop via DPP row rotates. Offsets d=1..7: each unordered pair once
    // (weight 2); d=8: pairs appear twice across j (weight 1).
    float acc2 = 0.0f, acc8 = 0.0f;
#define MBP_PAIR(D, ACC)                                                  \
    {                                                                     \
        const float ox = dpp_ror<D>(ux);                                  \
        const float oy = dpp_ror<D>(uy);                                  \
        const float oz = dpp_ror<D>(uz);                                  \
        const float ow = dpp_ror<D>(ejf);                                 \
        const float ka = sel3(ow, ka0, ka1, ka2);                         \
        const float c0 = sel3(ow, c00, c01, c02);                         \
        const float ct = ux * ox + uy * oy + uz * oz;                     \
        const float dd = ct - c0;                                         \
        ACC += ka * dd * dd;                                              \
    }
    MBP_PAIR(1, acc2) MBP_PAIR(2, acc2) MBP_PAIR(3, acc2) MBP_PAIR(4, acc2)
    MBP_PAIR(5, acc2) MBP_PAIR(6, acc2) MBP_PAIR(7, acc2) MBP_PAIR(8, acc8)
#undef MBP_PAIR

    float acc = active ? (2.0f * acc2 + acc8) : 0.0f;

    // Wave(64) shuffle -> block -> one partial per block (no contention).
    #pragma unroll
    for (int off = 32; off > 0; off >>= 1)
        acc += __shfl_down(acc, off, 64);
    if ((t & 63) == 0) wsum[t >> 6] = acc;
    __syncthreads();
    if (t == 0)
        partials[blockIdx.x] = wsum[0] + wsum[1] + wsum[2] + wsum[3];
}

__global__ __launch_bounds__(256) void mbp_reduce_kernel(
    const float* __restrict__ partials, float* __restrict__ out, int n)
{
    __shared__ float wsum[4];
    const int t = threadIdx.x;
    float acc = 0.0f;
    for (int i = t; i < n; i += 256) acc += partials[i];
    #pragma unroll
    for (int off = 32; off > 0; off >>= 1)
        acc += __shfl_down(acc, off, 64);
    if ((t & 63) == 0) wsum[t >> 6] = acc;
    __syncthreads();
    if (t == 0) out[0] = wsum[0] + wsum[1] + wsum[2] + wsum[3];
}

// ---------------- Fallback path (ws unavailable) ----------------------------
__global__ void mbp_zero_kernel(float* out) {
    if (threadIdx.x == 0) out[0] = 0.0f;
}

__global__ __launch_bounds__(256) void mbp_fallback_kernel(
    const float* __restrict__ pos, const int* __restrict__ target,
    const int* __restrict__ elem, const int* __restrict__ plt,
    const float* __restrict__ k_angle, const float* __restrict__ cos0,
    float* __restrict__ out, int n_atoms)
{
    __shared__ float  ka_tab[9];
    __shared__ float  c0_tab[9];
    __shared__ float4 s4[APB][DEG + 1];
    __shared__ float  wsum[4];
    const int t = threadIdx.x;
    if (t < 9) { const int p = plt[t]; ka_tab[t] = k_angle[p]; c0_tab[t] = cos0[p]; }
    const int a = t >> 4, j = t & 15;
    const int atom = blockIdx.x * APB + a;
    const bool active = (atom < n_atoms);
    float ux = 0.f, uy = 0.f, uz = 0.f; int ej = 0;
    if (active) {
        const float pix = pos[atom * 3], piy = pos[atom * 3 + 1], piz = pos[atom * 3 + 2];
        const int tj = target[atom * DEG + j];
        const float dx = pos[tj * 3] - pix, dy = pos[tj * 3 + 1] - piy, dz = pos[tj * 3 + 2] - piz;
        const float r2 = dx * dx + dy * dy + dz * dz;
        const float ri = (r2 > 0.f) ? rsqrtf(r2) : 0.f;
        ux = dx * ri; uy = dy * ri; uz = dz * ri;
        ej = elem[tj];
        s4[a][j] = make_float4(ux, uy, uz, (float)ej);
    }
    __syncthreads();
    float acc = 0.0f;
    if (active) {
        const int r = ej * 3;
        const float ka0 = ka_tab[r], ka1 = ka_tab[r + 1], ka2 = ka_tab[r + 2];
        const float c00 = c0_tab[r], c01 = c0_tab[r + 1], c02 = c0_tab[r + 2];
        float acc2 = 0.f, acc8 = 0.f;
        #pragma unroll
        for (int d = 1; d <= 8; ++d) {
            const int k = (j + d) & 15;
            const float4 o = s4[a][k];
            const float ka = (o.w == 1.0f) ? ka1 : ((o.w == 2.0f) ? ka2 : ka0);
            const float c0 = (o.w == 1.0f) ? c01 : ((o.w == 2.0f) ? c02 : c00);
            const float ct = ux * o.x + uy * o.y + uz * o.z;
            const float dd = ct - c0;
            const float en = ka * dd * dd;
            if (d < 8) acc2 += en; else acc8 = en;
        }
        acc = 2.0f * acc2 + acc8;
    }
    #pragma unroll
    for (int off = 32; off > 0; off >>= 1) acc += __shfl_down(acc, off, 64);
    if ((t & 63) == 0) wsum[t >> 6] = acc;
    __syncthreads();
    if (t == 0) atomicAdd(out, wsum[0] + wsum[1] + wsum[2] + wsum[3]);
}

extern "C" void kernel_launch(void* const* d_in, const int* in_sizes, int n_in,
                              void* d_out, int out_size, void* d_ws, size_t ws_size,
                              hipStream_t stream) {
    const float* pos     = (const float*)d_in[0];
    const int*   edge    = (const int*)d_in[1];   // (2, n_edges) flat
    const int*   elem    = (const int*)d_in[2];
    const int*   plt     = (const int*)d_in[3];
    const float* k_angle = (const float*)d_in[4];
    const float* cos0    = (const float*)d_in[5];
    float*       out     = (float*)d_out;

    const int n_atoms = in_sizes[0] / 3;
    const int n_edges = in_sizes[1] / 2;
    const int* target = edge + n_edges;           // edge_index[1]

    const int n_blocks = (n_atoms + APB - 1) / APB;   // 3125
    const bool ws_ok = (d_ws != nullptr) &&
                       (ws_size >= (size_t)n_blocks * sizeof(float));

    if (ws_ok) {
        float* partials = (float*)d_ws;
        ManyBodyPotential_85143431675992_kernel<<<n_blocks, TPB, 0, stream>>>(
            pos, target, elem, plt, k_angle, cos0, partials, n_atoms);
        mbp_reduce_kernel<<<1, 256, 0, stream>>>(partials, out, n_blocks);
    } else {
        mbp_zero_kernel<<<1, 64, 0, stream>>>(out);
        mbp_fallback_kernel<<<n_blocks, 256, 0, stream>>>(
            pos, target, elem, plt, k_angle, cos0, out, n_atoms);
    }
}

// Round 7
// 79.435 us; speedup vs baseline: 2.1421x; 1.0251x over previous
//
#include <hip/hip_runtime.h>

#define DEG 16
#define ATOMS_PER_BLOCK 16

// R6 = revert to the best-measured variant (R2, 79.6 us total).
// Session evidence: R3 (packed gather), R4 (cooperative single-launch,
// -113% regression), R5 (DPP in-register rotate, no LDS/barriers) all failed
// to beat this structure — the main kernel sits at the ~3-5 us
// launch/drain floor; the bench total is dominated by the harness's fixed
// 256 MiB d_ws re-poison fill (~41 us at 83% of HBM peak) + restores.

__global__ __launch_bounds__(256) void ManyBodyPotential_85143431675992_kernel(
    const float* __restrict__ pos,      // (n_atoms, 3)
    const int*   __restrict__ target,   // (n_atoms*DEG,)  = edge_index[1]
    const int*   __restrict__ elem,     // (n_atoms,)
    const int*   __restrict__ plt,      // (3,3) row-major, symmetric
    const float* __restrict__ k_angle,  // (6,)
    const float* __restrict__ cos0,     // (6,)
    float*       __restrict__ partials, // (gridDim.x,) distinct slots
    float*       __restrict__ out,      // fallback atomic target
    int n_atoms)
{
    __shared__ float  ka_tab[9];
    __shared__ float  c0_tab[9];
    // Per neighbor: unit vector + element-as-float in .w  (ds_read_b128)
    __shared__ float4 s4[ATOMS_PER_BLOCK][DEG + 1];   // +1 float4 row pad
    __shared__ float  wsum[4];

    const int t = threadIdx.x;
    if (t < 9) {
        const int p = plt[t];
        ka_tab[t] = k_angle[p];
        c0_tab[t] = cos0[p];
    }

    const int a    = t >> 4;             // local atom 0..15
    const int j    = t & 15;             // neighbor slot 0..15
    const int atom = blockIdx.x * ATOMS_PER_BLOCK + a;
    const bool active = (atom < n_atoms);

    float ux = 0.f, uy = 0.f, uz = 0.f;
    int   ej = 0;
    if (active) {
        const float pix = pos[atom * 3 + 0];
        const float piy = pos[atom * 3 + 1];
        const float piz = pos[atom * 3 + 2];
        const int   tj  = target[atom * DEG + j];      // coalesced
        const float dx  = pos[tj * 3 + 0] - pix;
        const float dy  = pos[tj * 3 + 1] - piy;
        const float dz  = pos[tj * 3 + 2] - piz;
        const float r2  = dx * dx + dy * dy + dz * dz;
        // r2==0 (self-edge / coincident atoms): reference gives cos=0 for any
        // pair involving this edge; zero unit vector reproduces that exactly.
        const float rinv = (r2 > 0.f) ? rsqrtf(r2) : 0.f;
        ux = dx * rinv; uy = dy * rinv; uz = dz * rinv;
        ej = elem[tj];
        s4[a][j] = make_float4(ux, uy, uz, (float)ej);
    }
    __syncthreads();

    float acc = 0.0f;
    if (active) {
        // Hoist this thread's (ej, *) coefficient row into registers.
        const int   r   = ej * 3;
        const float ka0 = ka_tab[r + 0], ka1 = ka_tab[r + 1], ka2 = ka_tab[r + 2];
        const float c00 = c0_tab[r + 0], c01 = c0_tab[r + 1], c02 = c0_tab[r + 2];

        // Symmetry: e(j,k)==e(k,j).  Offsets d=1..7 cover each unordered
        // pair once (weight 2); d=8 pairs appear twice across j (weight 1).
        float acc2 = 0.0f, acc8 = 0.0f;
        #pragma unroll
        for (int d = 1; d <= 8; ++d) {
            const int    k  = (j + d) & 15;
            const float4 o  = s4[a][k];
            const float  ka = (o.w == 1.0f) ? ka1 : ((o.w == 2.0f) ? ka2 : ka0);
            const float  c0 = (o.w == 1.0f) ? c01 : ((o.w == 2.0f) ? c02 : c00);
            const float  ct = ux * o.x + uy * o.y + uz * o.z;   // cos(theta)
            const float  dd = ct - c0;
            const float  e  = ka * dd * dd;
            if (d < 8) acc2 += e; else acc8 = e;
        }
        acc = 2.0f * acc2 + acc8;
    }

    // Wave(64) shuffle reduction -> block reduction -> one partial per block.
    #pragma unroll
    for (int off = 32; off > 0; off >>= 1)
        acc += __shfl_down(acc, off, 64);
    if ((t & 63) == 0) wsum[t >> 6] = acc;
    __syncthreads();
    if (t == 0) {
        const float s = wsum[0] + wsum[1] + wsum[2] + wsum[3];
        if (partials) partials[blockIdx.x] = s;
        else          atomicAdd(out, s);
    }
}

__global__ __launch_bounds__(1024) void mbp_reduce_kernel(
    const float* __restrict__ partials, float* __restrict__ out, int n)
{
    __shared__ float wsum[16];
    const int t = threadIdx.x;
    float acc = 0.0f;
    for (int i = t; i < n; i += 1024) acc += partials[i];
    #pragma unroll
    for (int off = 32; off > 0; off >>= 1)
        acc += __shfl_down(acc, off, 64);
    if ((t & 63) == 0) wsum[t >> 6] = acc;
    __syncthreads();
    if (t == 0) {
        float s = 0.0f;
        #pragma unroll
        for (int i = 0; i < 16; ++i) s += wsum[i];
        out[0] = s;
    }
}

__global__ void mbp_zero_kernel(float* out) {
    if (threadIdx.x == 0) out[0] = 0.0f;
}

extern "C" void kernel_launch(void* const* d_in, const int* in_sizes, int n_in,
                              void* d_out, int out_size, void* d_ws, size_t ws_size,
                              hipStream_t stream) {
    const float* pos     = (const float*)d_in[0];
    const int*   edge    = (const int*)d_in[1];   // (2, n_edges) flat
    const int*   elem    = (const int*)d_in[2];
    const int*   plt     = (const int*)d_in[3];
    const float* k_angle = (const float*)d_in[4];
    const float* cos0    = (const float*)d_in[5];
    float*       out     = (float*)d_out;

    const int n_atoms = in_sizes[0] / 3;
    const int n_edges = in_sizes[1] / 2;
    const int* target = edge + n_edges;           // edge_index[1]

    const int n_blocks = (n_atoms + ATOMS_PER_BLOCK - 1) / ATOMS_PER_BLOCK;  // 3125

    const bool ws_ok = (d_ws != nullptr) && (ws_size >= (size_t)n_blocks * sizeof(float));
    float* partials = ws_ok ? (float*)d_ws : nullptr;

    if (!ws_ok) mbp_zero_kernel<<<1, 64, 0, stream>>>(out);

    ManyBodyPotential_85143431675992_kernel<<<n_blocks, 256, 0, stream>>>(
        pos, target, elem, plt, k_angle, cos0, partials, out, n_atoms);

    if (ws_ok)
        mbp_reduce_kernel<<<1, 1024, 0, stream>>>(partials, out, n_blocks);
}